// Round 1
// baseline (234.339 us; speedup 1.0000x reference)
//
#include <hip/hip_runtime.h>

// LengthRegulator fused: B=32, T=512, C=384, MAX_LEN=4096 (fixed shapes).
// out[b,p,:] = x[b, t(p), :], t(p) = #{j : csum[b,j] <= p} (clip T-1),
// zero for p >= mel_len[b] = csum[b,T-1]; mel_len appended as float32.
//
// R(this): split setup (scan+search, once per batch, 32 blocks) from the
// stream (2048 blocks, pure gather-stream). The 1024-block version redid
// the 512-elem scan + 128 binary searches in EVERY block before streaming
// only 192 KiB; rocprof shows the harness poison fill (768 MiB) hits
// 6.6 TB/s with the same store pattern, so the stream should approach it
// once the prologue is ~free. Index table: int16, 256 KB in d_ws.
// Plain (cached) stores kept: NT stores measured +11 us in prior session.

#define B   32
#define T   512
#define C4  96          // C/4 = 384/4
#define ML  4096
#define PPB 64          // positions per stream block
#define TPB 384         // stream threads per block (6 waves)

typedef float v4f __attribute__((ext_vector_type(4)));
typedef unsigned short u16x8 __attribute__((ext_vector_type(8)));

// ---------------- kernel A: per-batch scan + full index table ----------------
__global__ __launch_bounds__(512)
void lr_setup_kernel(const int* __restrict__ dur,
                     short* __restrict__ idx,
                     float* __restrict__ mel_out) {
    __shared__ int s_cs[T];
    __shared__ int s_wsum[4];

    const int b    = blockIdx.x;
    const int tid  = threadIdx.x;
    const int lane = tid & 63;

    // scan: threads 0..255 hold 2 durations each; shuffle scan (as before)
    int pairsum = 0, d1 = 0;
    if (tid < 256) {
        int2 d2 = ((const int2*)(dur + b * T))[tid];
        int d0 = d2.x < 0 ? 0 : d2.x;
        d1     = d2.y < 0 ? 0 : d2.y;
        pairsum = d0 + d1;
    }
    int incl = pairsum;
    #pragma unroll
    for (int off = 1; off < 64; off <<= 1) {
        int n = __shfl_up(incl, off, 64);
        if (lane >= off) incl += n;
    }
    if (tid < 256 && lane == 63) s_wsum[tid >> 6] = incl;
    __syncthreads();
    if (tid < 256) {
        const int w = tid >> 6;
        int wp = 0;
        #pragma unroll
        for (int j = 0; j < 3; ++j) if (j < w) wp += s_wsum[j];
        const int S = incl + wp;               // inclusive csum through 2*tid+1
        s_cs[2 * tid + 1] = S;
        s_cs[2 * tid]     = S - d1;
    }
    __syncthreads();

    const int mel = s_cs[T - 1];
    if (tid == 0) mel_out[b] = (float)mel;

    // 8 consecutive positions per thread: one binary search, then walk.
    const int p0 = tid * 8;
    int lo = 0, hi = T;                        // first index with cs[i] > p0
    while (lo < hi) {
        int mid = (lo + hi) >> 1;
        if (s_cs[mid] <= p0) lo = mid + 1; else hi = mid;
    }
    int t = lo;
    u16x8 r;
    #pragma unroll
    for (int j = 0; j < 8; ++j) {
        const int p = p0 + j;
        if (p >= mel) {
            r[j] = 0xFFFFu;                    // zero-fill marker (-1 as short)
        } else {
            while (s_cs[t] <= p) ++t;          // monotone walk; t <= T-1 since cs[T-1]=mel>p
            r[j] = (unsigned short)(t < (T - 1) ? t : (T - 1));
        }
    }
    // coalesced: thread writes 16B at byte offset 16*tid
    *((u16x8*)(idx + (size_t)b * ML) + tid) = r;
}

// ---------------- kernel B: pure gather-stream ----------------
__global__ __launch_bounds__(TPB)
void lr_stream_kernel(const float* __restrict__ x,
                      const short* __restrict__ idx,
                      float* __restrict__ out) {
    __shared__ int s_idx[PPB];

    const int b     = blockIdx.x >> 6;         // / (ML/PPB) = /64
    const int ptile = blockIdx.x & 63;
    const int tid   = threadIdx.x;

    if (tid < PPB)
        s_idx[tid] = (int)idx[(size_t)b * ML + ptile * PPB + tid];  // sign-extends -1
    __syncthreads();

    const v4f* __restrict__ x4 = (const v4f*)x;
    v4f* __restrict__ o4 = (v4f*)out;
    const int sub = tid / 96;                  // 0..3
    const int c4  = tid - sub * 96;            // fixed float4 column
    const size_t xbase = (size_t)b * T * C4 + c4;
    const size_t obase = (size_t)b * ML * C4 + (size_t)(ptile * PPB) * C4 + c4;
    const v4f zero = (v4f){0.f, 0.f, 0.f, 0.f};

    #pragma unroll 8
    for (int k = 0; k < PPB / 4; ++k) {        // 16 iterations
        const int pl = 4 * k + sub;
        const int t  = s_idx[pl];              // LDS broadcast
        v4f val = zero;
        if (t >= 0) val = x4[xbase + (size_t)t * C4];
        o4[obase + (size_t)pl * C4] = val;
    }
}

// ---------------- fallback: previous fused kernel (ws too small) ----------------
__global__ __launch_bounds__(384)
void lr_fused_kernel(const float* __restrict__ x,
                     const int* __restrict__ dur,
                     float* __restrict__ out,
                     float* __restrict__ mel_out) {
    __shared__ int s_cs[T];
    __shared__ int s_wsum[4];
    __shared__ int s_idx[128];

    const int b     = blockIdx.x >> 5;
    const int ptile = blockIdx.x & 31;
    const int tid   = threadIdx.x;
    const int lane  = tid & 63;

    int pairsum = 0, d1 = 0;
    if (tid < 256) {
        int2 d2 = ((const int2*)(dur + b * T))[tid];
        int d0 = d2.x < 0 ? 0 : d2.x;
        d1     = d2.y < 0 ? 0 : d2.y;
        pairsum = d0 + d1;
    }
    int incl = pairsum;
    #pragma unroll
    for (int off = 1; off < 64; off <<= 1) {
        int n = __shfl_up(incl, off, 64);
        if (lane >= off) incl += n;
    }
    if (tid < 256 && lane == 63) s_wsum[tid >> 6] = incl;
    __syncthreads();
    if (tid < 256) {
        const int w = tid >> 6;
        int wp = 0;
        #pragma unroll
        for (int j = 0; j < 3; ++j) if (j < w) wp += s_wsum[j];
        const int S = incl + wp;
        s_cs[2 * tid + 1] = S;
        s_cs[2 * tid]     = S - d1;
    }
    __syncthreads();

    const int mel = s_cs[T - 1];
    if (ptile == 0 && tid == 0) mel_out[b] = (float)mel;

    if (tid < 128) {
        const int p = ptile * 128 + tid;
        int r = -1;
        if (p < mel) {
            int lo = 0, hi = T;
            while (lo < hi) {
                int mid = (lo + hi) >> 1;
                if (s_cs[mid] <= p) lo = mid + 1; else hi = mid;
            }
            r = lo < (T - 1) ? lo : (T - 1);
        }
        s_idx[tid] = r;
    }
    __syncthreads();

    const v4f* __restrict__ x4 = (const v4f*)x;
    v4f* __restrict__ o4 = (v4f*)out;
    const int sub = tid / 96;
    const int c4  = tid - sub * 96;
    const size_t xbase = (size_t)b * T * C4 + c4;
    const size_t obase = (size_t)b * ML * C4 + (size_t)ptile * 128 * C4 + c4;
    const v4f zero = (v4f){0.f, 0.f, 0.f, 0.f};

    #pragma unroll 8
    for (int k = 0; k < 128 / 4; ++k) {
        const int pl = 4 * k + sub;
        const int t  = s_idx[pl];
        v4f val = zero;
        if (t >= 0) val = x4[xbase + (size_t)t * C4];
        o4[obase + (size_t)pl * C4] = val;
    }
}

extern "C" void kernel_launch(void* const* d_in, const int* in_sizes, int n_in,
                              void* d_out, int out_size, void* d_ws, size_t ws_size,
                              hipStream_t stream) {
    const float* x   = (const float*)d_in[0];
    const int*   dur = (const int*)d_in[1];
    // d_in[2] = max_len (fixed 4096 for this bench)

    float* out     = (float*)d_out;                  // B*ML*C floats
    float* mel_out = out + (size_t)B * ML * C4 * 4;  // 32 floats (tail)

    const size_t idx_bytes = (size_t)B * ML * sizeof(short);  // 256 KB
    if (d_ws != nullptr && ws_size >= idx_bytes) {
        short* idx = (short*)d_ws;
        lr_setup_kernel<<<B, 512, 0, stream>>>(dur, idx, mel_out);
        lr_stream_kernel<<<B * (ML / PPB), TPB, 0, stream>>>(x, idx, out);
    } else {
        lr_fused_kernel<<<B * (ML / 128), 384, 0, stream>>>(x, dur, out, mel_out);
    }
}